// Round 10
// baseline (42.409 us; speedup 1.0000x reference)
//
#include <hip/hip_runtime.h>

// FFD cubic B-spline flow generation, separable (x -> y -> z), barrier-free,
// DRAM-stream-local tiling: each block owns ONE contiguous 41 KB output region
// (bc, single x, 64 consecutive y, all z), and linear block id maps linearly to
// memory -> concurrently-resident blocks write a compact sweeping window
// (fill-kernel-like), instead of 8 scattered 5KB chunks per block.
//
// mesh: [4][3][23][27][23] f32, out: [4][3][160][192][160] f32, spacing 8 all
// axes -> d=(i&7)/8 (8 weight rows shared by all axes), pivot = i>>3.
// (R6 lesson: non-temporal stores regress badly — plain stores only.)

#define SPX 160
#define SPY 192
#define SPZ 160
#define CPX 23
#define CPY 27
#define CPZ 23
#define MXS (CPY * CPZ)   // 621, mesh x-plane stride

#define TXS  8    // tXw cy-stride (words): [cz][8]
#define TXYS 37   // tXYw row stride (37*? mod 32 = 5, coprime -> <=2-way stage C)

// wave-local LDS sync: all prior DS ops retired -> data visible to this wave
#define WAVE_LDS_SYNC() asm volatile("s_waitcnt lgkmcnt(0)" ::: "memory")

__device__ __forceinline__ float4 bspline_w(float d) {
    float d2 = d * d, d3 = d2 * d, e = 1.0f - d;
    float4 w;
    w.x = e * e * e * (1.0f / 6.0f);
    w.y = 0.5f * d3 - d2 + (2.0f / 3.0f);
    w.z = -0.5f * d3 + 0.5f * d2 + 0.5f * d + (1.0f / 6.0f);
    w.w = d3 * (1.0f / 6.0f);
    return w;
}

__global__ __launch_bounds__(256, 8) void ffd_kernel(const float* __restrict__ mesh,
                                                     float* __restrict__ out) {
    const int yb   = blockIdx.x;   // 0..2   (y block of 64) — fastest => linear memory
    const int x    = blockIdx.y;   // 0..159 (single x value)
    const int bc   = blockIdx.z;   // 0..11  (b*3 + c)
    const int tid  = threadIdx.x;
    const int lane = tid & 63;
    const int wid  = tid >> 6;     // wave owns y rows [yb*64 + wid*16, +16)

    __shared__ float tXw[4][CPZ][TXS];    // [wave][cz][u], u = cy - cy0w, 5 used
    __shared__ float tXYw[4][16][TXYS];   // [wave][y8][cz]

    // ---- block-uniform x contraction parameters
    const int px = x >> 3;
    const float4 wx = bspline_w((float)(x & 7) * 0.125f);

    // ---- stage A: contract x. 115 values/wave: i = u*23 + cz (u=0..4, cz=0..22)
    // tXw[cz][u] = sum_a wx[a] * mesh[bc][px+a][cy0w+u][cz]
    const int cy0w = yb * 8 + 2 * wid;            // wave's first y-pivot
    const float* mbase = mesh + (size_t)bc * (CPX * CPY * CPZ)
                              + (size_t)px * MXS + (size_t)cy0w * CPZ;
    #pragma unroll
    for (int j = 0; j < 2; ++j) {
        int i = lane + 64 * j;
        if (j == 0 || lane < 115 - 64) {
            int u  = i / 23;                      // const-div -> magic mul
            int cz = i - 23 * u;
            const float* mp = mbase + u * CPZ + cz;
            float acc = wx.x * mp[0]
                      + wx.y * mp[MXS]
                      + wx.z * mp[2 * MXS]
                      + wx.w * mp[3 * MXS];
            tXw[wid][cz][u] = acc;
        }
    }
    WAVE_LDS_SYNC();

    // ---- stage B: contract y. 368 values/wave: i = cz*16 + y8 (shift-only).
    // tXY[y8][cz] = sum_b wy[b] * tX[cz][(y8>>3)+b]
    const int y8B = lane & 15;                    // lane-constant
    const int ub  = y8B >> 3;                     // 0 or 1
    const float4 wy = bspline_w((float)(y8B & 7) * 0.125f);
    #pragma unroll
    for (int j = 0; j < 6; ++j) {
        if (j < 5 || lane < 368 - 320) {
            int cz = (lane >> 4) + 4 * j;
            const float* tx = &tXw[wid][cz][ub];  // 8 distinct addrs/inst, broadcast
            tXYw[wid][y8B][cz] = wy.x * tx[0] + wy.y * tx[1]
                               + wy.z * tx[2] + wy.w * tx[3];
        }
    }
    WAVE_LDS_SYNC();

    // ---- stage C: expand z + store. lane = (r, zt); 8 lanes per y-row,
    // 8 rows per pass, 2 passes -> 16 rows/wave. Full 128B line per store inst;
    // per block the store stream is one contiguous 41 KB region.
    // out z = 32k + 4*zt + e' -> q = 4k + (zt>>1), W rows 4*(zt&1)..+3.
    const int zt = lane & 7;
    const int r  = lane >> 3;                     // 0..7
    const int h  = zt & 1;
    const int qo = zt >> 1;
    const float4 Wr0 = bspline_w((float)(4 * h + 0) * 0.125f);
    const float4 Wr1 = bspline_w((float)(4 * h + 1) * 0.125f);
    const float4 Wr2 = bspline_w((float)(4 * h + 2) * 0.125f);
    const float4 Wr3 = bspline_w((float)(4 * h + 3) * 0.125f);

    float* obase = out + ((size_t)(bc * SPX + x) * SPY
                        + (size_t)(yb * 64 + wid * 16)) * SPZ;
    #pragma unroll
    for (int pass = 0; pass < 2; ++pass) {
        int y8 = 8 * pass + r;
        const float* tcol = &tXYw[wid][y8][0];    // banks (5*r+qo)%32: <=2-way
        float* orow = obase + (size_t)y8 * SPZ;
        #pragma unroll
        for (int k = 0; k < 5; ++k) {
            int qa = 4 * k + qo;
            float m0 = tcol[qa];
            float m1 = tcol[qa + 1];
            float m2 = tcol[qa + 2];
            float m3 = tcol[qa + 3];
            float4 o;
            o.x = Wr0.x * m0 + Wr0.y * m1 + Wr0.z * m2 + Wr0.w * m3;
            o.y = Wr1.x * m0 + Wr1.y * m1 + Wr1.z * m2 + Wr1.w * m3;
            o.z = Wr2.x * m0 + Wr2.y * m1 + Wr2.z * m2 + Wr2.w * m3;
            o.w = Wr3.x * m0 + Wr3.y * m1 + Wr3.z * m2 + Wr3.w * m3;
            *(float4*)&orow[32 * k + 4 * zt] = o;
        }
    }
}

extern "C" void kernel_launch(void* const* d_in, const int* in_sizes, int n_in,
                              void* d_out, int out_size, void* d_ws, size_t ws_size,
                              hipStream_t stream) {
    const float* mesh = (const float*)d_in[0];
    float* out = (float*)d_out;
    dim3 grid(3, SPX, 4 * 3);   // (yb, x, bc) = 5760 blocks, linear id ~ linear memory
    ffd_kernel<<<grid, 256, 0, stream>>>(mesh, out);
}